// Round 7
// baseline (290.701 us; speedup 1.0000x reference)
//
#include <hip/hip_runtime.h>
#include <math.h>

// Problem shape (fixed by reference setup_inputs):
//   B=32, H=64, W=64, C=256, NHWC layout (C contiguous).
//   Outputs: x (B,H,W,C) fp32 then gate (B,1,1,C) fp32, concatenated flat.
#define B_ 32
#define HW_ 4096          // 64*64
#define C_ 256
#define C4_ 64            // C/4
#define KPB 16            // blocks (chunks) per batch
#define POS 256           // positions per block
#define RR 50             // rows held in registers per thread (200 VGPRs)
#define LR 14             // rows held in LDS per thread (14*4KB = 56KB/block)

// Native vector type — required for __builtin_nontemporal_store (HIP's
// float4 is a class and is rejected by the builtin).
typedef float vfloat4 __attribute__((ext_vector_type(4)));

__device__ inline vfloat4 vmax4(vfloat4 a, vfloat4 b) {
  vfloat4 r;
  r.x = fmaxf(a.x, b.x); r.y = fmaxf(a.y, b.y);
  r.z = fmaxf(a.z, b.z); r.w = fmaxf(a.w, b.w);
  return r;
}

// ---------------- Single-pass fused kernel ----------------
// Round-6 post-mortem: kernel PASSED at 105 us but VGPR_Count=128 revealed
// the compiler REMATERIALIZED the vr[] loads (in is const __restrict__)
// instead of retaining 200 VGPRs across the gate sync — phase 4 silently
// became a read+write pass (~46 us, read-rate-capped) instead of a pure
// NT-write (~20 us). FETCH=66.5 MB also showed the 2-pass structure's
// second read was already L3-deduplicated — so retention's win is the
// ~26 us phase-4 rate difference, not HBM bytes.
//
// FIX (rule-17 opaque pin): asm volatile("" : "+v"(x)) on every retained
// component after phase 1. The value becomes an opaque asm output — the
// compiler cannot substitute a reload of in[] for it, and with the
// __launch_bounds__(256,2) cap of 256 VGPRs (pressure ~230; 2 waves/SIMD
// x 230 = 460 <= 512 physical) the allocator holds it in registers.
//
// Structure: 512 blocks x 256 threads; block (b,k) owns 256 positions
// (256 KB): 50 float4 rows/thread in VGPRs + 14 rows in LDS (64 KB
// static). __launch_bounds__(256,2) + 64KB LDS => 2 blocks/CU => all 512
// blocks co-resident BY CONSTRUCTION => intra-grid sync cannot deadlock.
//
// Sync protocol (validated rounds 2-6 — NO __threadfence, which triggers
// a ~190us buffer_wbl2 L2-flush storm on gfx950): AGENT-scope relaxed
// atomic stores (coherent at L3, no flush) + per-wave s_waitcnt vmcnt(0)
// drain + agent-scope counter bump; last arriver computes the gate; the
// round-5 race fix (__syncthreads between ALL waves' drains and t0's flag
// release) is kept verbatim.
//
// Thread layout: t = pg*64 + c4; row i (i=0..63) is position p = 4*i+pg;
// lanes = 64 consecutive float4 channel-groups -> 1KB coalesced/row.
__global__ __launch_bounds__(256, 2) void fused_gate_kernel(
    const float* __restrict__ in, float* __restrict__ ws_sum,
    float* __restrict__ ws_max, float* __restrict__ ws_gate,
    unsigned int* __restrict__ counters, unsigned int* __restrict__ flags,
    const float* __restrict__ factor, const float* __restrict__ W1,
    const float* __restrict__ b1, const float* __restrict__ gamma,
    const float* __restrict__ beta, const float* __restrict__ bn_mean,
    const float* __restrict__ bn_var, const float* __restrict__ Wg,
    const float* __restrict__ bg, const float* __restrict__ gumbel,
    float* __restrict__ out_x, float* __restrict__ out_gate) {
  const int blk = blockIdx.x;
  const int b = blk >> 4;          // / KPB
  const int k = blk & 15;          // % KPB
  const int t = threadIdx.x;
  const int c4 = t & 63;
  const int pg = t >> 6;           // 0..3 == wave id

  // Static LDS, exactly 64 KB:
  //   s_data[14*256] : retained rows        (57344 B)
  //   s_red[512]     : cross-wave reduce    ( 8192 B)
  // Overlays inside s_red (all placed where the reduce never reads, or
  // dead after it; every cross-use is fenced by __syncthreads):
  //   flag slot  = ((int*)&s_red[1])   (s_red[1] never read by reduce)
  //   poolv[256] = (float*)&s_red[64]  (red_s[64..127] dead after reduce)
  //   gatev[256] = (float*)&s_red[128]
  __shared__ vfloat4 s_data[LR * 256];
  __shared__ vfloat4 s_red[512];
  vfloat4* red_s = s_red;          // [256] sums
  vfloat4* red_m = s_red + 256;    // [256] maxes
  int*   wflag = (int*)&s_red[1];
  float* poolv = (float*)&s_red[64];
  float* gatev = (float*)&s_red[128];

  const vfloat4* in4 = (const vfloat4*)in;
  vfloat4* out4 = (vfloat4*)out_x;
  const long base = (long)b * (HW_ * C4_) + (long)(k * POS + pg) * C4_ + c4;

  // ---- Phase 1: single read of this block's 256 KB; retain on-chip ----
  vfloat4 vr[RR];
#pragma unroll
  for (int i = 0; i < RR; ++i) vr[i] = in4[base + (long)(i * 4) * C4_];

  vfloat4 s = {0.f, 0.f, 0.f, 0.f};
  vfloat4 m = {-INFINITY, -INFINITY, -INFINITY, -INFINITY};
#pragma unroll
  for (int i = 0; i < LR; ++i) {
    vfloat4 v = in4[base + (long)((RR + i) * 4) * C4_];
    s_data[i * 256 + pg * 64 + c4] = v;
    s += v;
    m = vmax4(m, v);
  }
#pragma unroll
  for (int i = 0; i < RR; ++i) { s += vr[i]; m = vmax4(m, vr[i]); }

  // Opaque pin (round-7 fix): forbid rematerialization of vr from global.
  // Empty asm, zero instructions; "+v" makes each value an opaque register
  // def the compiler must carry to phase 4.
#pragma unroll
  for (int i = 0; i < RR; ++i) {
    asm volatile("" : "+v"(vr[i].x), "+v"(vr[i].y), "+v"(vr[i].z),
                      "+v"(vr[i].w));
  }

  // ---- Phase 2: cross-wave reduce, publish chunk partial ----
  red_s[t] = s;
  red_m[t] = m;
  __syncthreads();

  if (pg == 0) {  // wave 0 only (t == c4) — per-wave drain is sufficient here
#pragma unroll
    for (int q = 1; q < 4; ++q) {
      s += red_s[q * 64 + c4];
      m = vmax4(m, red_m[q * 64 + c4]);
    }
    // Agent-scope stores: coherent at L3 once vmcnt retires, no L2 flush.
    const int o = ((b * KPB + k) * C4_ + c4) * 4;
    __hip_atomic_store(&ws_sum[o + 0], s.x, __ATOMIC_RELAXED, __HIP_MEMORY_SCOPE_AGENT);
    __hip_atomic_store(&ws_sum[o + 1], s.y, __ATOMIC_RELAXED, __HIP_MEMORY_SCOPE_AGENT);
    __hip_atomic_store(&ws_sum[o + 2], s.z, __ATOMIC_RELAXED, __HIP_MEMORY_SCOPE_AGENT);
    __hip_atomic_store(&ws_sum[o + 3], s.w, __ATOMIC_RELAXED, __HIP_MEMORY_SCOPE_AGENT);
    __hip_atomic_store(&ws_max[o + 0], m.x, __ATOMIC_RELAXED, __HIP_MEMORY_SCOPE_AGENT);
    __hip_atomic_store(&ws_max[o + 1], m.y, __ATOMIC_RELAXED, __HIP_MEMORY_SCOPE_AGENT);
    __hip_atomic_store(&ws_max[o + 2], m.z, __ATOMIC_RELAXED, __HIP_MEMORY_SCOPE_AGENT);
    __hip_atomic_store(&ws_max[o + 3], m.w, __ATOMIC_RELAXED, __HIP_MEMORY_SCOPE_AGENT);
    asm volatile("s_waitcnt vmcnt(0)" ::: "memory");  // drain, THEN bump
    if (t == 0) {
      unsigned prev = __hip_atomic_fetch_add(&counters[b], 1u,
                                             __ATOMIC_RELAXED,
                                             __HIP_MEMORY_SCOPE_AGENT);
      *wflag = (prev == KPB - 1) ? 1 : 0;
    }
  }
  __syncthreads();
  const int winner = *wflag;  // block-uniform
  __syncthreads();

  vfloat4 g4v;
  if (winner) {
    // ---- Phase 3w: last block of batch b computes the gate ----
    const int j = t;  // channel
    float sj = 0.f;
    float mj = -INFINITY;
#pragma unroll
    for (int kk = 0; kk < KPB; ++kk) {
      float ps = __hip_atomic_load(&ws_sum[(b * KPB + kk) * C_ + j],
                                   __ATOMIC_RELAXED, __HIP_MEMORY_SCOPE_AGENT);
      float pm = __hip_atomic_load(&ws_max[(b * KPB + kk) * C_ + j],
                                   __ATOMIC_RELAXED, __HIP_MEMORY_SCOPE_AGENT);
      sj += ps;
      mj = fmaxf(mj, pm);
    }

    // softmax over the 2 blend factors
    float a0 = factor[0], a1 = factor[1];
    float mx = fmaxf(a0, a1);
    float e0 = expf(a0 - mx), e1 = expf(a1 - mx);
    float inv = 1.f / (e0 + e1);
    float f0 = e0 * inv, f1 = e1 * inv;

    poolv[j] = (sj * (1.0f / (float)HW_)) * f0 + mj * f1;
    __syncthreads();

    // h[j] = sum_c pool[c] * W1[c,j] + b1[j]; 4 FMA chains for ILP
    float h0 = 0.f, h1 = 0.f, h2 = 0.f, h3 = 0.f;
#pragma unroll 8
    for (int c = 0; c < C_; c += 4) {
      h0 = fmaf(poolv[c + 0], W1[(c + 0) * C_ + j], h0);
      h1 = fmaf(poolv[c + 1], W1[(c + 1) * C_ + j], h1);
      h2 = fmaf(poolv[c + 2], W1[(c + 2) * C_ + j], h2);
      h3 = fmaf(poolv[c + 3], W1[(c + 3) * C_ + j], h3);
    }
    float h = ((h0 + h1) + (h2 + h3)) + b1[j];
    // BatchNorm (inference) + ReLU
    h = gamma[j] * (h - bn_mean[j]) * rsqrtf(bn_var[j] + 1e-3f) + beta[j];
    h = fmaxf(h, 0.f);

    // grouped 1x1 conv -> 2 logits, + gumbel; gate = 1 iff z1 > z0
    float z0 = fmaf(h, Wg[j * 2 + 0], bg[j * 2 + 0]) + gumbel[(b * C_ + j) * 2 + 0];
    float z1 = fmaf(h, Wg[j * 2 + 1], bg[j * 2 + 1]) + gumbel[(b * C_ + j) * 2 + 1];
    float g = (z1 > z0) ? 1.0f : 0.0f;

    gatev[j] = g;
    out_gate[b * C_ + j] = g;
    __hip_atomic_store(&ws_gate[b * C_ + j], g, __ATOMIC_RELAXED,
                       __HIP_MEMORY_SCOPE_AGENT);
    // Each wave drains ITS OWN gate stores to the coherence point...
    asm volatile("s_waitcnt vmcnt(0)" ::: "memory");
    // ...then the block barrier guarantees ALL waves have drained (the
    // round-5 race fix), and only then may t0 release the flag.
    __syncthreads();
    if (t == 0)
      __hip_atomic_store(&flags[b], 1u, __ATOMIC_RELAXED,
                         __HIP_MEMORY_SCOPE_AGENT);
    // gatev[] LDS writes are visible block-wide via the barrier above.
    g4v.x = gatev[c4 * 4 + 0];
    g4v.y = gatev[c4 * 4 + 1];
    g4v.z = gatev[c4 * 4 + 2];
    g4v.w = gatev[c4 * 4 + 3];
  } else {
    // ---- Phase 3s: siblings wait for the gate (all co-resident) ----
    if (t == 0) {
      while (__hip_atomic_load(&flags[b], __ATOMIC_RELAXED,
                               __HIP_MEMORY_SCOPE_AGENT) == 0u)
        __builtin_amdgcn_s_sleep(2);
    }
    __syncthreads();  // all threads ordered after t0's flag observation
    g4v.x = __hip_atomic_load(&ws_gate[b * C_ + c4 * 4 + 0], __ATOMIC_RELAXED, __HIP_MEMORY_SCOPE_AGENT);
    g4v.y = __hip_atomic_load(&ws_gate[b * C_ + c4 * 4 + 1], __ATOMIC_RELAXED, __HIP_MEMORY_SCOPE_AGENT);
    g4v.z = __hip_atomic_load(&ws_gate[b * C_ + c4 * 4 + 2], __ATOMIC_RELAXED, __HIP_MEMORY_SCOPE_AGENT);
    g4v.w = __hip_atomic_load(&ws_gate[b * C_ + c4 * 4 + 3], __ATOMIC_RELAXED, __HIP_MEMORY_SCOPE_AGENT);
  }

  // ---- Phase 4: multiply retained data by gate, NT-store (pure write) ----
#pragma unroll
  for (int i = 0; i < RR; ++i) {
    vfloat4 v = vr[i] * g4v;
    __builtin_nontemporal_store(v, &out4[base + (long)(i * 4) * C4_]);
  }
#pragma unroll
  for (int i = 0; i < LR; ++i) {
    vfloat4 v = s_data[i * 256 + pg * 64 + c4] * g4v;
    __builtin_nontemporal_store(v, &out4[base + (long)((RR + i) * 4) * C4_]);
  }
}

extern "C" void kernel_launch(void* const* d_in, const int* in_sizes, int n_in,
                              void* d_out, int out_size, void* d_ws, size_t ws_size,
                              hipStream_t stream) {
  const float* inputs  = (const float*)d_in[0];
  const float* factor  = (const float*)d_in[1];
  const float* W1      = (const float*)d_in[2];
  const float* b1      = (const float*)d_in[3];
  const float* gamma   = (const float*)d_in[4];
  const float* beta    = (const float*)d_in[5];
  const float* bn_mean = (const float*)d_in[6];
  const float* bn_var  = (const float*)d_in[7];
  const float* Wg      = (const float*)d_in[8];
  const float* bg      = (const float*)d_in[9];
  const float* gumbel  = (const float*)d_in[10];

  float* out_x = (float*)d_out;                          // B*H*W*C floats
  float* out_gate = (float*)d_out + (long)B_ * HW_ * C_; // B*C floats

  // Workspace layout (floats):
  float* ws_sum  = (float*)d_ws;                   // B*KPB*C = 131072
  float* ws_max  = ws_sum + B_ * KPB * C_;         // 131072
  float* ws_gate = ws_max + B_ * KPB * C_;         // B*C = 8192
  unsigned int* counters = (unsigned int*)(ws_gate + B_ * C_);  // B uints
  unsigned int* flags    = counters + B_;                        // B uints

  // Workspace is poisoned between iterations -> counters+flags must be
  // zeroed. 256-byte async memset is graph-capturable (stream memset node).
  hipMemsetAsync(counters, 0, 2 * B_ * sizeof(unsigned int), stream);

  fused_gate_kernel<<<B_ * KPB, 256, 0, stream>>>(
      inputs, ws_sum, ws_max, ws_gate, counters, flags, factor, W1, b1,
      gamma, beta, bn_mean, bn_var, Wg, bg, gumbel, out_x, out_gate);
}